// Round 1
// baseline (505.833 us; speedup 1.0000x reference)
//
#include <hip/hip_runtime.h>

// Problem: B=32, S=4096, H=768, fp32.
// start_logits[b,s] = sum_h hidden[b,s,h] * w_start[h]
// end_logits[b,s]   = sum_h hidden[b,s,h] * w_end[h]
// Output: concat(start_logits, end_logits) flat -> 2*B*S floats.
//
// Strategy: memory-bound streaming reduce. One wave64 per row of H=768.
// Lane i loads float4 at element offsets {0,256,512} + 4*lane (coalesced,
// 16B/lane/instr), FMAs against cached w fragments, butterfly shfl reduce.

#define BS_ROWS (32 * 4096)   // 131072 rows
#define HDIM 768

__global__ __launch_bounds__(256) void qa_logits_kernel(
    const float* __restrict__ hs,
    const float* __restrict__ w_start,
    const float* __restrict__ w_end,
    float* __restrict__ out) {

    const int gtid = blockIdx.x * blockDim.x + threadIdx.x;
    const int wave = gtid >> 6;          // one wave per row
    const int lane = threadIdx.x & 63;

    const float* __restrict__ row = hs + (size_t)wave * HDIM;

    float s = 0.f, e = 0.f;

#pragma unroll
    for (int k = 0; k < 3; ++k) {
        const int idx = k * 256 + lane * 4;   // 64 lanes * float4 = 256 elems/step
        const float4 h = *(const float4*)(row + idx);
        const float4 a = *(const float4*)(w_start + idx);
        const float4 b = *(const float4*)(w_end + idx);
        s += h.x * a.x + h.y * a.y + h.z * a.z + h.w * a.w;
        e += h.x * b.x + h.y * b.y + h.z * b.z + h.w * b.w;
    }

    // 64-lane butterfly reduction for both accumulators.
#pragma unroll
    for (int off = 32; off > 0; off >>= 1) {
        s += __shfl_xor(s, off, 64);
        e += __shfl_xor(e, off, 64);
    }

    if (lane == 0) {
        out[wave] = s;            // start_logits
        out[BS_ROWS + wave] = e;  // end_logits
    }
}

extern "C" void kernel_launch(void* const* d_in, const int* in_sizes, int n_in,
                              void* d_out, int out_size, void* d_ws, size_t ws_size,
                              hipStream_t stream) {
    const float* hs      = (const float*)d_in[0];
    const float* w_start = (const float*)d_in[1];
    const float* w_end   = (const float*)d_in[2];
    float* out = (float*)d_out;

    // 131072 rows, 1 wave/row, 4 waves/block -> 32768 blocks of 256 threads.
    const int blocks = BS_ROWS / 4;
    qa_logits_kernel<<<blocks, 256, 0, stream>>>(hs, w_start, w_end, out);
}

// Round 2
// 486.900 us; speedup vs baseline: 1.0389x; 1.0389x over previous
//
#include <hip/hip_runtime.h>

// Problem: B=32, S=4096, H=768, fp32.
// start_logits[b,s] = sum_h hidden[b,s,h] * w_start[h]
// end_logits[b,s]   = sum_h hidden[b,s,h] * w_end[h]
// Output: concat(start, end) flat -> 2*B*S floats.
//
// Memory-bound streaming reduce: 402.7 MB hidden read, 1 MB write.
// HBM floor @6.3 TB/s ~ 64 us.
//
// Structure: persistent wave64 handles 16 CONSECUTIVE rows.
//  - weight fragments (3x float4 each) hoisted to registers once per wave
//    (kills 6 of 9 VMEM instrs/row vs the one-row-per-wave version)
//  - hidden loads: nontemporal float4, lane i covers elems {0,256,512}+4i
//    (fully coalesced 1 KiB/instr; nt keeps the 402 MB stream out of L2)
//  - XOR butterfly leaves the full sum on ALL lanes -> lane r keeps row r's
//    result; after 16 rows, lanes 0..15 do ONE coalesced 64 B store per output.

#define ROWS (32 * 4096)       // 131072
#define HDIM 768
#define ROWS_PER_WAVE 16

typedef float f32x4 __attribute__((ext_vector_type(4)));

__global__ __launch_bounds__(256) void qa_logits_kernel(
    const float* __restrict__ hs,
    const float* __restrict__ w_start,
    const float* __restrict__ w_end,
    float* __restrict__ out) {

    const int lane = threadIdx.x & 63;
    const int wave = (blockIdx.x * blockDim.x + threadIdx.x) >> 6;
    const int row0 = wave * ROWS_PER_WAVE;

    // Weight fragments: constant per lane, loaded once, L1-broadcast.
    f32x4 wa[3], wb[3];
#pragma unroll
    for (int k = 0; k < 3; ++k) {
        wa[k] = *(const f32x4*)(w_start + k * 256 + lane * 4);
        wb[k] = *(const f32x4*)(w_end   + k * 256 + lane * 4);
    }

    float s_keep = 0.f, e_keep = 0.f;
    const float* __restrict__ base = hs + (size_t)row0 * HDIM + lane * 4;

#pragma unroll 4
    for (int r = 0; r < ROWS_PER_WAVE; ++r) {
        const float* __restrict__ row = base + (size_t)r * HDIM;
        float s = 0.f, e = 0.f;
#pragma unroll
        for (int k = 0; k < 3; ++k) {
            const f32x4 h = __builtin_nontemporal_load((const f32x4*)(row + k * 256));
            s += h.x * wa[k].x + h.y * wa[k].y + h.z * wa[k].z + h.w * wa[k].w;
            e += h.x * wb[k].x + h.y * wb[k].y + h.z * wb[k].z + h.w * wb[k].w;
        }
        // Butterfly: full sum lands on every lane.
#pragma unroll
        for (int off = 32; off > 0; off >>= 1) {
            s += __shfl_xor(s, off, 64);
            e += __shfl_xor(e, off, 64);
        }
        if (lane == r) { s_keep = s; e_keep = e; }
    }

    // Coalesced 64 B stores: lanes 0..15 hold rows row0..row0+15.
    if (lane < ROWS_PER_WAVE) {
        out[row0 + lane] = s_keep;
        out[ROWS + row0 + lane] = e_keep;
    }
}

extern "C" void kernel_launch(void* const* d_in, const int* in_sizes, int n_in,
                              void* d_out, int out_size, void* d_ws, size_t ws_size,
                              hipStream_t stream) {
    const float* hs      = (const float*)d_in[0];
    const float* w_start = (const float*)d_in[1];
    const float* w_end   = (const float*)d_in[2];
    float* out = (float*)d_out;

    // 131072 rows / 16 rows-per-wave = 8192 waves = 2048 blocks x 4 waves.
    const int blocks = ROWS / (ROWS_PER_WAVE * 4);
    qa_logits_kernel<<<blocks, 256, 0, stream>>>(hs, w_start, w_end, out);
}